// Round 2
// baseline (246.197 us; speedup 1.0000x reference)
//
#include <hip/hip_runtime.h>
#include <cstdint>

// Problem constants (from reference setup_inputs)
#define BATCH   16
#define CCH     512
#define DD      32
#define NCODES  16384
#define HWSZ    1024            // 32*32
#define P_TOTAL 16384           // BATCH * HWSZ
#define NCHUNK  32
#define CHUNK   (NCODES / NCHUNK)   // 512 codes per chunk

typedef _Float16 half8 __attribute__((ext_vector_type(8)));
typedef float    f32x4 __attribute__((ext_vector_type(4)));

union H8 { _Float16 h[8]; uint4 u; };
union L8 { uint4 u; half8 h; };

// f16 split row layout: row = 128 B = [32 f16 hi | 32 f16 lo], values scaled
// by 2^12 so lo-terms stay in f16 normal range. sim accumulates at scale
// 2^24; argmax is scale-invariant. 4 exact product terms -> ~2^-22 rel err.

// ---------------------------------------------------------------------------
// Kernel PREP (fused): grid 384 blocks x 256 thr.
//   blocks [0,256):  proj  z[p][d] = sum_c enc*pw + pb, invz, zf16 split rows
//                    (c-loop explicitly double-buffered: 16 loads in flight
//                     while FMAs run on the previous 16)
//   blocks [256,320): enorm en rows + ef16 split rows
//   blocks [320,384): zero hist + scalarAcc (loss, entropy, done-counter)
// ---------------------------------------------------------------------------
__global__ __launch_bounds__(256) void prep_kernel(
    const float* __restrict__ enc, const float* __restrict__ pw,
    const float* __restrict__ pb, const float* __restrict__ emb,
    float* __restrict__ z, float* __restrict__ invz, char* __restrict__ zf16,
    float* __restrict__ en, char* __restrict__ ef16,
    int* __restrict__ hist, float* __restrict__ scalarAcc)
{
    const int t = threadIdx.x;

    if (blockIdx.x >= 320) {                 // ---- hist/scalar zeroing ----
        const int i = (blockIdx.x - 320) * 256 + t;
        hist[i] = 0;
        if (blockIdx.x == 320 && t < 4) scalarAcc[t] = 0.f;
        return;
    }

    if (blockIdx.x >= 256) {                 // ---- enorm ----
        const int r = (blockIdx.x - 256) * 256 + t;
        const float4* src = reinterpret_cast<const float4*>(emb + (size_t)r * DD);
        float4 v[8];
        float ssq = 0.f;
#pragma unroll
        for (int q = 0; q < 8; q++) {
            v[q] = src[q];
            ssq += v[q].x * v[q].x + v[q].y * v[q].y + v[q].z * v[q].z + v[q].w * v[q].w;
        }
        const float inv = 1.f / fmaxf(sqrtf(ssq), 1e-6f);
        float4* dst = reinterpret_cast<float4*>(en + (size_t)r * DD);
        char* row = ef16 + (size_t)r * 128;
#pragma unroll
        for (int q = 0; q < 8; q += 2) {
            H8 hi, lo;
#pragma unroll
            for (int u = 0; u < 2; u++) {
                float4 o;
                o.x = v[q + u].x * inv; o.y = v[q + u].y * inv;
                o.z = v[q + u].z * inv; o.w = v[q + u].w * inv;
                dst[q + u] = o;
                const float s[4] = {o.x * 4096.f, o.y * 4096.f, o.z * 4096.f, o.w * 4096.f};
#pragma unroll
                for (int j = 0; j < 4; j++) {
                    const _Float16 h = (_Float16)s[j];
                    hi.h[u * 4 + j] = h;
                    lo.h[u * 4 + j] = (_Float16)(s[j] - (float)h);
                }
            }
            *(uint4*)(row + q * 8)      = hi.u;
            *(uint4*)(row + 64 + q * 8) = lo.u;
        }
        return;
    }

    // ---- proj ----
    const int hw_l = t & 63;
    const int dg   = __builtin_amdgcn_readfirstlane(t >> 6);   // SGPR-uniform
    const int p0   = blockIdx.x * 64;
    const int b    = p0 >> 10;
    const int hw   = (p0 & 1023) + hw_l;
    const float* encb = enc + (size_t)b * (CCH * HWSZ) + hw;

    float acc[8];
#pragma unroll
    for (int j = 0; j < 8; j++) acc[j] = 0.f;

    float ev[16];
#pragma unroll
    for (int u = 0; u < 16; u++) ev[u] = encb[(size_t)u * HWSZ];

    for (int c0 = 0; c0 < CCH - 16; c0 += 16) {
        float nv[16];
#pragma unroll
        for (int u = 0; u < 16; u++)             // next batch in flight
            nv[u] = encb[(size_t)(c0 + 16 + u) * HWSZ];
#pragma unroll
        for (int u = 0; u < 16; u++)
#pragma unroll
            for (int j = 0; j < 8; j++)          // uniform -> s_load
                acc[j] = fmaf(ev[u], pw[(dg * 8 + j) * CCH + c0 + u], acc[j]);
#pragma unroll
        for (int u = 0; u < 16; u++) ev[u] = nv[u];
    }
#pragma unroll
    for (int u = 0; u < 16; u++)                 // final batch
#pragma unroll
        for (int j = 0; j < 8; j++)
            acc[j] = fmaf(ev[u], pw[(dg * 8 + j) * CCH + (CCH - 16) + u], acc[j]);

    const int p = p0 + hw_l;
    float ssq = 0.f;
    H8 hi, lo;
#pragma unroll
    for (int j = 0; j < 8; j++) {
        const float v = acc[j] + pb[dg * 8 + j];
        z[(size_t)p * DD + dg * 8 + j] = v;
        ssq = fmaf(v, v, ssq);
        const float vs = v * 4096.f;
        const _Float16 h = (_Float16)vs;
        hi.h[j] = h;
        lo.h[j] = (_Float16)(vs - (float)h);
    }
    char* row = zf16 + (size_t)p * 128;
    *(uint4*)(row + dg * 16)      = hi.u;
    *(uint4*)(row + 64 + dg * 16) = lo.u;

    __shared__ float red[4][64];
    red[dg][hw_l] = ssq;
    __syncthreads();
    if (t < 64) {
        const float tot = red[0][t] + red[1][t] + red[2][t] + red[3][t];
        invz[p0 + t] = 1.f / fmaxf(sqrtf(tot), 1e-6f);
    }
}

// ---------------------------------------------------------------------------
// Kernel C: fused MFMA sims + argmax over one 512-code chunk.
// R8: 8-independent-MFMA stages (R7's proven per-wave ILP win) AT 4 blocks/CU
// residency: __launch_bounds__(256,4) pins total regs <=128/wave (R7's (,3)
// let the allocator balloon to a 3-wave cap -> occupancy 39% ate the ILP
// gain; 2048 blocks / 4-resident = exactly 2 clean scheduling rounds).
// Manual 2x-unroll with statically-named A/B load buffers removes the 16
// per-iteration register copies. Last A-load (iter 16) is dead/garbage and
// over-reads <40KB into the 2MB pval region: read-only, never consumed.
// best/bidx split per code-tile, merged post-loop with idx tie-break.
// D layout: code=(lane>>4)*4+reg, pos=lane&15; shfl_xor(16,32) reduce with
// equal->lower-idx tie-break (numpy first-occurrence).
// ---------------------------------------------------------------------------
__global__ __launch_bounds__(256, 4) void argmax_kernel(
    const char* __restrict__ zf16, const char* __restrict__ ef16,
    float* __restrict__ pval, int* __restrict__ pidx)
{
    const int w    = threadIdx.x >> 6;       // wave 0..3
    const int lane = threadIdx.x & 63;
    const int col  = lane & 15;
    const int quad = lane >> 4;
    const int chunk = (blockIdx.x & 7) * 4 + (blockIdx.x >> 9);  // XCD swizzle
    const int pg    = (blockIdx.x >> 3) & 63;
    const int wp0   = pg * 256 + w * 64;     // wave position base (64 pos)

    // B fragments (z): pos-tile tt rows wp0 + tt*16 + col
    half8 bh[4], bl[4];
#pragma unroll
    for (int tt = 0; tt < 4; tt++) {
        const char* r = zf16 + (size_t)(wp0 + tt * 16 + col) * 128 + quad * 16;
        L8 a; a.u = *(const uint4*)(r);       bh[tt] = a.h;
        L8 b; b.u = *(const uint4*)(r + 64);  bl[tt] = b.h;
    }

    const int n0 = chunk * CHUNK;
    const char* abase = ef16 + (size_t)(n0 + col) * 128 + quad * 16;

    float best[2][4];
    int   bidx[2][4];
#pragma unroll
    for (int ct = 0; ct < 2; ct++)
#pragma unroll
        for (int tt = 0; tt < 4; tt++) { best[ct][tt] = -3e38f; bidx[ct][tt] = 0; }

    const f32x4 zero4 = {0.f, 0.f, 0.f, 0.f};

    // compute one iteration (2 code-tiles = 32 codes) from 4 raw uint4 regs.
    // 4 stages x 8 independent MFMAs; 8 independent compare chains.
#define TILE_COMPUTE(C0H, C0L, C1H, C1L, CODE0)                               \
    {                                                                         \
        L8 u0h, u0l, u1h, u1l;                                                \
        u0h.u = (C0H); u0l.u = (C0L); u1h.u = (C1H); u1l.u = (C1L);           \
        const half8 a0h = u0h.h, a0l = u0l.h, a1h = u1h.h, a1l = u1l.h;       \
        f32x4 acc[2][4];                                                      \
        _Pragma("unroll")                                                     \
        for (int tt = 0; tt < 4; tt++)                                        \
            acc[0][tt] = __builtin_amdgcn_mfma_f32_16x16x32_f16(a0h, bh[tt], zero4, 0, 0, 0); \
        _Pragma("unroll")                                                     \
        for (int tt = 0; tt < 4; tt++)                                        \
            acc[1][tt] = __builtin_amdgcn_mfma_f32_16x16x32_f16(a1h, bh[tt], zero4, 0, 0, 0); \
        _Pragma("unroll")                                                     \
        for (int tt = 0; tt < 4; tt++)                                        \
            acc[0][tt] = __builtin_amdgcn_mfma_f32_16x16x32_f16(a0h, bl[tt], acc[0][tt], 0, 0, 0); \
        _Pragma("unroll")                                                     \
        for (int tt = 0; tt < 4; tt++)                                        \
            acc[1][tt] = __builtin_amdgcn_mfma_f32_16x16x32_f16(a1h, bl[tt], acc[1][tt], 0, 0, 0); \
        _Pragma("unroll")                                                     \
        for (int tt = 0; tt < 4; tt++)                                        \
            acc[0][tt] = __builtin_amdgcn_mfma_f32_16x16x32_f16(a0l, bh[tt], acc[0][tt], 0, 0, 0); \
        _Pragma("unroll")                                                     \
        for (int tt = 0; tt < 4; tt++)                                        \
            acc[1][tt] = __builtin_amdgcn_mfma_f32_16x16x32_f16(a1l, bh[tt], acc[1][tt], 0, 0, 0); \
        _Pragma("unroll")                                                     \
        for (int tt = 0; tt < 4; tt++)                                        \
            acc[0][tt] = __builtin_amdgcn_mfma_f32_16x16x32_f16(a0l, bl[tt], acc[0][tt], 0, 0, 0); \
        _Pragma("unroll")                                                     \
        for (int tt = 0; tt < 4; tt++)                                        \
            acc[1][tt] = __builtin_amdgcn_mfma_f32_16x16x32_f16(a1l, bl[tt], acc[1][tt], 0, 0, 0); \
        _Pragma("unroll")                                                     \
        for (int ct = 0; ct < 2; ct++)                                        \
            _Pragma("unroll")                                                 \
            for (int tt = 0; tt < 4; tt++)                                    \
                _Pragma("unroll")                                             \
                for (int r = 0; r < 4; r++) {                                 \
                    const float v = acc[ct][tt][r];                           \
                    if (v > best[ct][tt]) { best[ct][tt] = v; bidx[ct][tt] = (CODE0) + ct * 16 + r; } \
                }                                                             \
    }

    // double-buffered pipeline, statically-named buffers (no reg copies)
    uint4 A0h = *(const uint4*)(abase);
    uint4 A0l = *(const uint4*)(abase + 64);
    uint4 A1h = *(const uint4*)(abase + 2048);
    uint4 A1l = *(const uint4*)(abase + 2048 + 64);
    uint4 B0h, B0l, B1h, B1l;

    const int codeBase = n0 + quad * 4;      // lane's reg-0 code, ctile0 iter0
    for (int it = 0; it < 16; it += 2) {
        const char* pB = abase + (size_t)(it + 1) * 4096;
        B0h = *(const uint4*)(pB);
        B0l = *(const uint4*)(pB + 64);
        B1h = *(const uint4*)(pB + 2048);
        B1l = *(const uint4*)(pB + 2048 + 64);

        TILE_COMPUTE(A0h, A0l, A1h, A1l, codeBase + it * 32);

        // it=14 -> iter-16 load: dead garbage, over-reads into pval pad (safe)
        const char* pA = abase + (size_t)(it + 2) * 4096;
        A0h = *(const uint4*)(pA);
        A0l = *(const uint4*)(pA + 64);
        A1h = *(const uint4*)(pA + 2048);
        A1l = *(const uint4*)(pA + 2048 + 64);

        TILE_COMPUTE(B0h, B0l, B1h, B1l, codeBase + it * 32 + 32);
    }
#undef TILE_COMPUTE

    // merge the two code-tile chains (idx tie-break: either idx can be lower)
    float fb[4];
    int   fi[4];
#pragma unroll
    for (int tt = 0; tt < 4; tt++) {
        float b0 = best[0][tt]; int i0 = bidx[0][tt];
        const float b1 = best[1][tt]; const int i1 = bidx[1][tt];
        if (b1 > b0 || (b1 == b0 && i1 < i0)) { b0 = b1; i0 = i1; }
        fb[tt] = b0; fi[tt] = i0;
    }

    // reduce across the 4 quads holding the same position (xor 16, 32)
#pragma unroll
    for (int off = 16; off < 64; off <<= 1) {
#pragma unroll
        for (int tt = 0; tt < 4; tt++) {
            const float ov = __shfl_xor(fb[tt], off);
            const int   oi = __shfl_xor(fi[tt], off);
            if (ov > fb[tt] || (ov == fb[tt] && oi < fi[tt])) {
                fb[tt] = ov; fi[tt] = oi;
            }
        }
    }
    if (quad == 0) {
#pragma unroll
        for (int tt = 0; tt < 4; tt++) {
            pval[(size_t)chunk * P_TOTAL + wp0 + tt * 16 + col] = fb[tt];
            pidx[(size_t)chunk * P_TOTAL + wp0 + tt * 16 + col] = fi[tt];
        }
    }
}

// ---------------------------------------------------------------------------
// Kernel COMBEX (fused combine + expand): 256 blocks x 512 thr, 64 pos each.
// Phase 1 (all 8 waves): per-position partial argmax over 4 chunks/kgroup.
// Phase 2 (wave 0): finalize argmax (idx-compare tie-break = lowest code on
// equal value, correct since chunk idx ranges are ordered), hist atomic,
// quantization-loss (shfl-reduced), stage en[idx] rows into LDS.
// Phase 3 (all): out[b][c][hw] = lat . exp_w[c] + exp_b[c]; ew via s_load.
// idx never round-trips through global memory.
// ---------------------------------------------------------------------------
__global__ __launch_bounds__(512) void combex_kernel(
    const float* __restrict__ pval, const int* __restrict__ pidx,
    const float* __restrict__ z, const float* __restrict__ invz,
    const float* __restrict__ en, const float* __restrict__ ew,
    const float* __restrict__ eb,
    int* __restrict__ hist, float* __restrict__ scalarAcc,
    float* __restrict__ out)
{
    const int t  = threadIdx.x;
    const int p0 = blockIdx.x * 64;

    __shared__ float lat[64 * 33];
    __shared__ float bvs[8][64];
    __shared__ int   bis[8][64];

    {   // phase 1: 8 kgroups x 4 chunks, ascending k (strict > = lowest k)
        const int pl = t & 63;
        const int kg = t >> 6;
        const int p  = p0 + pl;
        float best = -3e38f;
        int   bi   = 0;
#pragma unroll
        for (int k = 0; k < 4; k++) {
            const float v = pval[(size_t)(kg * 4 + k) * P_TOTAL + p];
            const int   i = pidx[(size_t)(kg * 4 + k) * P_TOTAL + p];
            if (v > best) { best = v; bi = i; }
        }
        bvs[kg][pl] = best;
        bis[kg][pl] = bi;
    }
    __syncthreads();

    if (t < 64) {   // phase 2 (wave 0)
        float best = bvs[0][t];
        int   bi   = bis[0][t];
#pragma unroll
        for (int kg = 1; kg < 8; kg++) {
            const float v = bvs[kg][t];
            const int   i = bis[kg][t];
            if (v > best || (v == best && i < bi)) { best = v; bi = i; }
        }
        const int p = p0 + t;
        atomicAdd(&hist[bi], 1);

        const float iv = invz[p];
        const float4* zsrc = reinterpret_cast<const float4*>(z + (size_t)p * DD);
        const float4* esrc = reinterpret_cast<const float4*>(en + (size_t)bi * DD);
        float ls = 0.f;
#pragma unroll
        for (int q = 0; q < 8; q++) {
            const float4 zv = zsrc[q];
            const float4 ev = esrc[q];
            lat[t * 33 + q * 4 + 0] = ev.x;
            lat[t * 33 + q * 4 + 1] = ev.y;
            lat[t * 33 + q * 4 + 2] = ev.z;
            lat[t * 33 + q * 4 + 3] = ev.w;
            const float dx = zv.x * iv - ev.x;
            const float dy = zv.y * iv - ev.y;
            const float dz = zv.z * iv - ev.z;
            const float dw = zv.w * iv - ev.w;
            ls += dx * dx + dy * dy + dz * dz + dw * dw;
        }
#pragma unroll
        for (int off = 32; off > 0; off >>= 1) ls += __shfl_down(ls, off);
        if (t == 0) atomicAdd(&scalarAcc[0], ls);
    }
    __syncthreads();

    // phase 3: expand — 8 waves x 64 c each
    const int hw_l = t & 63;
    const int cg   = __builtin_amdgcn_readfirstlane(t >> 6);   // 0..7
    float lr[32];
#pragma unroll
    for (int d = 0; d < DD; d++) lr[d] = lat[hw_l * 33 + d];

    const int b   = p0 >> 10;
    const int hw0 = p0 & 1023;
    float* outb = out + (size_t)b * (CCH * HWSZ) + hw0 + hw_l;
    const int c0 = cg * 64;
#pragma unroll 4
    for (int k = 0; k < 64; k++) {
        const int c = c0 + k;
        const float* ewc = ew + (size_t)c * DD;      // uniform -> s_load
        float s0 = 0.f, s1 = 0.f, s2 = 0.f, s3 = 0.f;
#pragma unroll
        for (int d = 0; d < DD; d += 4) {
            s0 = fmaf(lr[d + 0], ewc[d + 0], s0);
            s1 = fmaf(lr[d + 1], ewc[d + 1], s1);
            s2 = fmaf(lr[d + 2], ewc[d + 2], s2);
            s3 = fmaf(lr[d + 3], ewc[d + 3], s3);
        }
        outb[(size_t)c * HWSZ] = (s0 + s1) + (s2 + s3) + eb[c];
    }
}

// ---------------------------------------------------------------------------
// Kernel ENTROPY: 64 blocks x 256 thr, one hist element each. Last block
// (device-scope done-counter) finalizes both scalar outputs — agent-scope
// atomic loads dodge stale per-XCD L2 lines.
// ---------------------------------------------------------------------------
__global__ __launch_bounds__(256) void entropy_kernel(
    const int* __restrict__ hist, float* __restrict__ scalarAcc,
    float* __restrict__ out_scalars)
{
    const int i = blockIdx.x * 256 + threadIdx.x;
    const float u = (float)hist[i] * (1.f / (float)P_TOTAL);
    float h = -u * logf(u + 1e-6f);
    __shared__ float red[256];
    red[threadIdx.x] = h;
    __syncthreads();
    for (int s = 128; s > 0; s >>= 1) {
        if (threadIdx.x < s) red[threadIdx.x] += red[threadIdx.x + s];
        __syncthreads();
    }
    if (threadIdx.x == 0) {
        atomicAdd(&scalarAcc[1], red[0]);
        __threadfence();
        int* cnt = (int*)(scalarAcc + 2);
        const int prev = atomicAdd(cnt, 1);
        if (prev == 63) {    // last block: all adds are visible
            const float loss = __hip_atomic_load(&scalarAcc[0], __ATOMIC_RELAXED,
                                                 __HIP_MEMORY_SCOPE_AGENT);
            const float ent  = __hip_atomic_load(&scalarAcc[1], __ATOMIC_RELAXED,
                                                 __HIP_MEMORY_SCOPE_AGENT);
            out_scalars[0] = loss * (1.f / (float)(P_TOTAL * DD));
            out_scalars[1] = expf(ent);
        }
    }
}

// ---------------------------------------------------------------------------
// Workspace layout (bytes):
//   z      @ 0        : 16384*32*4  = 2,097,152
//   invz   @ 2097152  : 16384*4     =    65,536
//   en     @ 2162688  : 16384*32*4  = 2,097,152
//   zf16   @ 4259840  : 16384*128   = 2,097,152  (hi|lo f16 rows, x4096)
//   ef16   @ 6356992  : 16384*128   = 2,097,152
//   pval   @ 8454144  : 32*16384*4  = 2,097,152  (also argmax over-read pad)
//   pidx   @ 10551296 : 32*16384*4  = 2,097,152
//   hist   @ 12648448 : 16384*4     =    65,536
//   scalarAcc @ 12713984 : 4*4  (loss, entropy, done-counter, pad)
//   total ~12.7 MB
// ---------------------------------------------------------------------------
extern "C" void kernel_launch(void* const* d_in, const int* in_sizes, int n_in,
                              void* d_out, int out_size, void* d_ws, size_t ws_size,
                              hipStream_t stream)
{
    const float* enc = (const float*)d_in[0];   // [16,512,32,32]
    const float* emb = (const float*)d_in[1];   // [16384,32]
    const float* pw  = (const float*)d_in[2];   // [32,512]
    const float* pb  = (const float*)d_in[3];   // [32]
    const float* ew  = (const float*)d_in[4];   // [512,32]
    const float* eb  = (const float*)d_in[5];   // [512]
    float* out = (float*)d_out;                 // 8388608 + loss + perplexity

    char* ws = (char*)d_ws;
    float* z         = (float*)(ws + 0);
    float* invz      = (float*)(ws + 2097152);
    float* en        = (float*)(ws + 2162688);
    char*  zf16      = ws + 4259840;
    char*  ef16      = ws + 6356992;
    float* pval      = (float*)(ws + 8454144);
    int*   pidx      = (int*)  (ws + 10551296);
    int*   hist      = (int*)  (ws + 12648448);
    float* scalarAcc = (float*)(ws + 12713984);

    prep_kernel   <<<384, 256, 0, stream>>>(enc, pw, pb, emb, z, invz, zf16,
                                            en, ef16, hist, scalarAcc);
    argmax_kernel <<<64 * NCHUNK, 256, 0, stream>>>(zf16, ef16, pval, pidx);
    combex_kernel <<<P_TOTAL / 64, 512, 0, stream>>>(pval, pidx, z, invz, en,
                                                     ew, eb, hist, scalarAcc, out);
    entropy_kernel<<<NCODES / 256, 256, 0, stream>>>(hist, scalarAcc,
                                                     out + 8388608);
}

// Round 4
// 246.144 us; speedup vs baseline: 1.0002x; 1.0002x over previous
//
#include <hip/hip_runtime.h>
#include <cstdint>

// Problem constants (from reference setup_inputs)
#define BATCH   16
#define CCH     512
#define DD      32
#define NCODES  16384
#define HWSZ    1024            // 32*32
#define P_TOTAL 16384           // BATCH * HWSZ
#define NCHUNK  32
#define CHUNK   (NCODES / NCHUNK)   // 512 codes per chunk

typedef _Float16 half8 __attribute__((ext_vector_type(8)));
typedef float    f32x4 __attribute__((ext_vector_type(4)));

union H8 { _Float16 h[8]; uint4 u; };
union L8 { uint4 u; half8 h; };

// f16 split row layout: row = 128 B = [32 f16 hi | 32 f16 lo], values scaled
// by 2^12 so lo-terms stay in f16 normal range. sim accumulates at scale
// 2^24; argmax is scale-invariant. 4 exact product terms -> ~2^-22 rel err.

// ---------------------------------------------------------------------------
// Kernel PREP (fused): grid 384 blocks x 256 thr.
//   blocks [0,256):  proj  z[p][d] = sum_c enc*pw + pb, invz, zf16 split rows
//                    (c-loop explicitly double-buffered: 16 loads in flight
//                     while FMAs run on the previous 16)
//   blocks [256,320): enorm en rows + ef16 split rows
//   blocks [320,384): zero hist + scalarAcc (loss, entropy, done-counter)
// ---------------------------------------------------------------------------
__global__ __launch_bounds__(256) void prep_kernel(
    const float* __restrict__ enc, const float* __restrict__ pw,
    const float* __restrict__ pb, const float* __restrict__ emb,
    float* __restrict__ z, float* __restrict__ invz, char* __restrict__ zf16,
    float* __restrict__ en, char* __restrict__ ef16,
    int* __restrict__ hist, float* __restrict__ scalarAcc)
{
    const int t = threadIdx.x;

    if (blockIdx.x >= 320) {                 // ---- hist/scalar zeroing ----
        const int i = (blockIdx.x - 320) * 256 + t;
        hist[i] = 0;
        if (blockIdx.x == 320 && t < 4) scalarAcc[t] = 0.f;
        return;
    }

    if (blockIdx.x >= 256) {                 // ---- enorm ----
        const int r = (blockIdx.x - 256) * 256 + t;
        const float4* src = reinterpret_cast<const float4*>(emb + (size_t)r * DD);
        float4 v[8];
        float ssq = 0.f;
#pragma unroll
        for (int q = 0; q < 8; q++) {
            v[q] = src[q];
            ssq += v[q].x * v[q].x + v[q].y * v[q].y + v[q].z * v[q].z + v[q].w * v[q].w;
        }
        const float inv = 1.f / fmaxf(sqrtf(ssq), 1e-6f);
        float4* dst = reinterpret_cast<float4*>(en + (size_t)r * DD);
        char* row = ef16 + (size_t)r * 128;
#pragma unroll
        for (int q = 0; q < 8; q += 2) {
            H8 hi, lo;
#pragma unroll
            for (int u = 0; u < 2; u++) {
                float4 o;
                o.x = v[q + u].x * inv; o.y = v[q + u].y * inv;
                o.z = v[q + u].z * inv; o.w = v[q + u].w * inv;
                dst[q + u] = o;
                const float s[4] = {o.x * 4096.f, o.y * 4096.f, o.z * 4096.f, o.w * 4096.f};
#pragma unroll
                for (int j = 0; j < 4; j++) {
                    const _Float16 h = (_Float16)s[j];
                    hi.h[u * 4 + j] = h;
                    lo.h[u * 4 + j] = (_Float16)(s[j] - (float)h);
                }
            }
            *(uint4*)(row + q * 8)      = hi.u;
            *(uint4*)(row + 64 + q * 8) = lo.u;
        }
        return;
    }

    // ---- proj ----
    const int hw_l = t & 63;
    const int dg   = __builtin_amdgcn_readfirstlane(t >> 6);   // SGPR-uniform
    const int p0   = blockIdx.x * 64;
    const int b    = p0 >> 10;
    const int hw   = (p0 & 1023) + hw_l;
    const float* encb = enc + (size_t)b * (CCH * HWSZ) + hw;

    float acc[8];
#pragma unroll
    for (int j = 0; j < 8; j++) acc[j] = 0.f;

    float ev[16];
#pragma unroll
    for (int u = 0; u < 16; u++) ev[u] = encb[(size_t)u * HWSZ];

    for (int c0 = 0; c0 < CCH - 16; c0 += 16) {
        float nv[16];
#pragma unroll
        for (int u = 0; u < 16; u++)             // next batch in flight
            nv[u] = encb[(size_t)(c0 + 16 + u) * HWSZ];
#pragma unroll
        for (int u = 0; u < 16; u++)
#pragma unroll
            for (int j = 0; j < 8; j++)          // uniform -> s_load
                acc[j] = fmaf(ev[u], pw[(dg * 8 + j) * CCH + c0 + u], acc[j]);
#pragma unroll
        for (int u = 0; u < 16; u++) ev[u] = nv[u];
    }
#pragma unroll
    for (int u = 0; u < 16; u++)                 // final batch
#pragma unroll
        for (int j = 0; j < 8; j++)
            acc[j] = fmaf(ev[u], pw[(dg * 8 + j) * CCH + (CCH - 16) + u], acc[j]);

    const int p = p0 + hw_l;
    float ssq = 0.f;
    H8 hi, lo;
#pragma unroll
    for (int j = 0; j < 8; j++) {
        const float v = acc[j] + pb[dg * 8 + j];
        z[(size_t)p * DD + dg * 8 + j] = v;
        ssq = fmaf(v, v, ssq);
        const float vs = v * 4096.f;
        const _Float16 h = (_Float16)vs;
        hi.h[j] = h;
        lo.h[j] = (_Float16)(vs - (float)h);
    }
    char* row = zf16 + (size_t)p * 128;
    *(uint4*)(row + dg * 16)      = hi.u;
    *(uint4*)(row + 64 + dg * 16) = lo.u;

    __shared__ float red[4][64];
    red[dg][hw_l] = ssq;
    __syncthreads();
    if (t < 64) {
        const float tot = red[0][t] + red[1][t] + red[2][t] + red[3][t];
        invz[p0 + t] = 1.f / fmaxf(sqrtf(tot), 1e-6f);
    }
}

// ---------------------------------------------------------------------------
// Kernel C: fused MFMA sims + argmax over one 512-code chunk.
// R10 = R7 verbatim (hardware-verified passing, 83.5us): 2 code-tiles per
// iteration -> every MFMA stage has 8 INDEPENDENT ops; best/bidx state
// split per code-tile (merged post-loop with idx tie-break); 2048 blocks,
// XCD-locality chunk swizzle, 1-iteration (4x16B) prefetch.
// D layout: code=(lane>>4)*4+reg, pos=lane&15; shfl_xor(16,32) reduce with
// equal->lower-idx tie-break (numpy first-occurrence).
// ---------------------------------------------------------------------------
__global__ __launch_bounds__(256, 3) void argmax_kernel(
    const char* __restrict__ zf16, const char* __restrict__ ef16,
    float* __restrict__ pval, int* __restrict__ pidx)
{
    const int w    = threadIdx.x >> 6;       // wave 0..3
    const int lane = threadIdx.x & 63;
    const int col  = lane & 15;
    const int quad = lane >> 4;
    const int chunk = (blockIdx.x & 7) * 4 + (blockIdx.x >> 9);  // XCD swizzle
    const int pg    = (blockIdx.x >> 3) & 63;
    const int wp0   = pg * 256 + w * 64;     // wave position base (64 pos)

    // B fragments (z): pos-tile tt rows wp0 + tt*16 + col
    half8 bh[4], bl[4];
#pragma unroll
    for (int tt = 0; tt < 4; tt++) {
        const char* r = zf16 + (size_t)(wp0 + tt * 16 + col) * 128 + quad * 16;
        L8 a; a.u = *(const uint4*)(r);       bh[tt] = a.h;
        L8 b; b.u = *(const uint4*)(r + 64);  bl[tt] = b.h;
    }

    const int n0 = chunk * CHUNK;
    const char* abase = ef16 + (size_t)(n0 + col) * 128 + quad * 16;

    float best[2][4];
    int   bidx[2][4];
#pragma unroll
    for (int ct = 0; ct < 2; ct++)
#pragma unroll
        for (int tt = 0; tt < 4; tt++) { best[ct][tt] = -3e38f; bidx[ct][tt] = 0; }

    int code = n0 + quad * 4;                // lane's reg-0 code, ctile0 iter0

    // current-iteration A fragments (2 code tiles x hi/lo)
    uint4 c0h = *(const uint4*)(abase);
    uint4 c0l = *(const uint4*)(abase + 64);
    uint4 c1h = *(const uint4*)(abase + 2048);
    uint4 c1l = *(const uint4*)(abase + 2048 + 64);
    const f32x4 zero4 = {0.f, 0.f, 0.f, 0.f};

    for (int it = 0; it < 16; ++it) {
        // prefetch next iteration (last iter over-reads <5KB into pval: safe)
        const char* nx = abase + (size_t)(it + 1) * 4096;
        uint4 n0h = *(const uint4*)(nx);
        uint4 n0l = *(const uint4*)(nx + 64);
        uint4 n1h = *(const uint4*)(nx + 2048);
        uint4 n1l = *(const uint4*)(nx + 2048 + 64);

        L8 u0h, u0l, u1h, u1l;
        u0h.u = c0h; u0l.u = c0l; u1h.u = c1h; u1l.u = c1l;
        const half8 a0h = u0h.h, a0l = u0l.h, a1h = u1h.h, a1l = u1l.h;

        f32x4 acc[2][4];
        // stage 0: hh (8 independent MFMAs)
#pragma unroll
        for (int tt = 0; tt < 4; tt++)
            acc[0][tt] = __builtin_amdgcn_mfma_f32_16x16x32_f16(a0h, bh[tt], zero4, 0, 0, 0);
#pragma unroll
        for (int tt = 0; tt < 4; tt++)
            acc[1][tt] = __builtin_amdgcn_mfma_f32_16x16x32_f16(a1h, bh[tt], zero4, 0, 0, 0);
        // stage 1: hl
#pragma unroll
        for (int tt = 0; tt < 4; tt++)
            acc[0][tt] = __builtin_amdgcn_mfma_f32_16x16x32_f16(a0h, bl[tt], acc[0][tt], 0, 0, 0);
#pragma unroll
        for (int tt = 0; tt < 4; tt++)
            acc[1][tt] = __builtin_amdgcn_mfma_f32_16x16x32_f16(a1h, bl[tt], acc[1][tt], 0, 0, 0);
        // stage 2: lh
#pragma unroll
        for (int tt = 0; tt < 4; tt++)
            acc[0][tt] = __builtin_amdgcn_mfma_f32_16x16x32_f16(a0l, bh[tt], acc[0][tt], 0, 0, 0);
#pragma unroll
        for (int tt = 0; tt < 4; tt++)
            acc[1][tt] = __builtin_amdgcn_mfma_f32_16x16x32_f16(a1l, bh[tt], acc[1][tt], 0, 0, 0);
        // stage 3: ll
#pragma unroll
        for (int tt = 0; tt < 4; tt++)
            acc[0][tt] = __builtin_amdgcn_mfma_f32_16x16x32_f16(a0l, bl[tt], acc[0][tt], 0, 0, 0);
#pragma unroll
        for (int tt = 0; tt < 4; tt++)
            acc[1][tt] = __builtin_amdgcn_mfma_f32_16x16x32_f16(a1l, bl[tt], acc[1][tt], 0, 0, 0);

        // 8 independent compare chains (strict > keeps earliest = lowest code)
#pragma unroll
        for (int ct = 0; ct < 2; ct++)
#pragma unroll
            for (int tt = 0; tt < 4; tt++)
#pragma unroll
                for (int r = 0; r < 4; r++) {
                    const float v = acc[ct][tt][r];
                    if (v > best[ct][tt]) { best[ct][tt] = v; bidx[ct][tt] = code + ct * 16 + r; }
                }

        c0h = n0h; c0l = n0l; c1h = n1h; c1l = n1l;
        code += 32;
    }

    // merge the two code-tile chains (idx tie-break: ct0 iter5 vs ct1 iter3
    // can tie with either idx lower -> full compare)
    float fb[4];
    int   fi[4];
#pragma unroll
    for (int tt = 0; tt < 4; tt++) {
        float b0 = best[0][tt]; int i0 = bidx[0][tt];
        const float b1 = best[1][tt]; const int i1 = bidx[1][tt];
        if (b1 > b0 || (b1 == b0 && i1 < i0)) { b0 = b1; i0 = i1; }
        fb[tt] = b0; fi[tt] = i0;
    }

    // reduce across the 4 quads holding the same position (xor 16, 32)
#pragma unroll
    for (int off = 16; off < 64; off <<= 1) {
#pragma unroll
        for (int tt = 0; tt < 4; tt++) {
            const float ov = __shfl_xor(fb[tt], off);
            const int   oi = __shfl_xor(fi[tt], off);
            if (ov > fb[tt] || (ov == fb[tt] && oi < fi[tt])) {
                fb[tt] = ov; fi[tt] = oi;
            }
        }
    }
    if (quad == 0) {
#pragma unroll
        for (int tt = 0; tt < 4; tt++) {
            pval[(size_t)chunk * P_TOTAL + wp0 + tt * 16 + col] = fb[tt];
            pidx[(size_t)chunk * P_TOTAL + wp0 + tt * 16 + col] = fi[tt];
        }
    }
}

// ---------------------------------------------------------------------------
// Kernel COMBEX (fused combine + expand): 256 blocks x 512 thr, 64 pos each.
// Phase 1 (all 8 waves): per-position partial argmax over 4 chunks/kgroup.
// Phase 2 (wave 0): finalize argmax (idx-compare tie-break = lowest code on
// equal value, correct since chunk idx ranges are ordered), hist atomic,
// quantization-loss (shfl-reduced), stage en[idx] rows into LDS.
// Phase 3 (all): out[b][c][hw] = lat . exp_w[c] + exp_b[c]; ew via s_load.
// idx never round-trips through global memory.
// ---------------------------------------------------------------------------
__global__ __launch_bounds__(512) void combex_kernel(
    const float* __restrict__ pval, const int* __restrict__ pidx,
    const float* __restrict__ z, const float* __restrict__ invz,
    const float* __restrict__ en, const float* __restrict__ ew,
    const float* __restrict__ eb,
    int* __restrict__ hist, float* __restrict__ scalarAcc,
    float* __restrict__ out)
{
    const int t  = threadIdx.x;
    const int p0 = blockIdx.x * 64;

    __shared__ float lat[64 * 33];
    __shared__ float bvs[8][64];
    __shared__ int   bis[8][64];

    {   // phase 1: 8 kgroups x 4 chunks, ascending k (strict > = lowest k)
        const int pl = t & 63;
        const int kg = t >> 6;
        const int p  = p0 + pl;
        float best = -3e38f;
        int   bi   = 0;
#pragma unroll
        for (int k = 0; k < 4; k++) {
            const float v = pval[(size_t)(kg * 4 + k) * P_TOTAL + p];
            const int   i = pidx[(size_t)(kg * 4 + k) * P_TOTAL + p];
            if (v > best) { best = v; bi = i; }
        }
        bvs[kg][pl] = best;
        bis[kg][pl] = bi;
    }
    __syncthreads();

    if (t < 64) {   // phase 2 (wave 0)
        float best = bvs[0][t];
        int   bi   = bis[0][t];
#pragma unroll
        for (int kg = 1; kg < 8; kg++) {
            const float v = bvs[kg][t];
            const int   i = bis[kg][t];
            if (v > best || (v == best && i < bi)) { best = v; bi = i; }
        }
        const int p = p0 + t;
        atomicAdd(&hist[bi], 1);

        const float iv = invz[p];
        const float4* zsrc = reinterpret_cast<const float4*>(z + (size_t)p * DD);
        const float4* esrc = reinterpret_cast<const float4*>(en + (size_t)bi * DD);
        float ls = 0.f;
#pragma unroll
        for (int q = 0; q < 8; q++) {
            const float4 zv = zsrc[q];
            const float4 ev = esrc[q];
            lat[t * 33 + q * 4 + 0] = ev.x;
            lat[t * 33 + q * 4 + 1] = ev.y;
            lat[t * 33 + q * 4 + 2] = ev.z;
            lat[t * 33 + q * 4 + 3] = ev.w;
            const float dx = zv.x * iv - ev.x;
            const float dy = zv.y * iv - ev.y;
            const float dz = zv.z * iv - ev.z;
            const float dw = zv.w * iv - ev.w;
            ls += dx * dx + dy * dy + dz * dz + dw * dw;
        }
#pragma unroll
        for (int off = 32; off > 0; off >>= 1) ls += __shfl_down(ls, off);
        if (t == 0) atomicAdd(&scalarAcc[0], ls);
    }
    __syncthreads();

    // phase 3: expand — 8 waves x 64 c each
    const int hw_l = t & 63;
    const int cg   = __builtin_amdgcn_readfirstlane(t >> 6);   // 0..7
    float lr[32];
#pragma unroll
    for (int d = 0; d < DD; d++) lr[d] = lat[hw_l * 33 + d];

    const int b   = p0 >> 10;
    const int hw0 = p0 & 1023;
    float* outb = out + (size_t)b * (CCH * HWSZ) + hw0 + hw_l;
    const int c0 = cg * 64;
#pragma unroll 4
    for (int k = 0; k < 64; k++) {
        const int c = c0 + k;
        const float* ewc = ew + (size_t)c * DD;      // uniform -> s_load
        float s0 = 0.f, s1 = 0.f, s2 = 0.f, s3 = 0.f;
#pragma unroll
        for (int d = 0; d < DD; d += 4) {
            s0 = fmaf(lr[d + 0], ewc[d + 0], s0);
            s1 = fmaf(lr[d + 1], ewc[d + 1], s1);
            s2 = fmaf(lr[d + 2], ewc[d + 2], s2);
            s3 = fmaf(lr[d + 3], ewc[d + 3], s3);
        }
        outb[(size_t)c * HWSZ] = (s0 + s1) + (s2 + s3) + eb[c];
    }
}

// ---------------------------------------------------------------------------
// Kernel ENTROPY (R10): SINGLE block, 1024 threads, 16 hist entries each.
// Race-free by construction: no cross-block done-counter, no fences.
// combex's atomicAdds (hist, scalarAcc[0]) are visible via stream-ordered
// kernel boundaries. Shared-mem tree + wave shuffle reduce; thread 0
// writes both scalar outputs.
// ---------------------------------------------------------------------------
__global__ __launch_bounds__(1024) void entropy_kernel(
    const int* __restrict__ hist, const float* __restrict__ scalarAcc,
    float* __restrict__ out_scalars)
{
    const int t = threadIdx.x;
    float h = 0.f;
#pragma unroll
    for (int k = 0; k < 16; k++) {
        const float u = (float)hist[t + k * 1024] * (1.f / (float)P_TOTAL);
        h += -u * logf(u + 1e-6f);
    }
    __shared__ float red[1024];
    red[t] = h;
    __syncthreads();
#pragma unroll
    for (int s = 512; s >= 64; s >>= 1) {
        if (t < s) red[t] += red[t + s];
        __syncthreads();
    }
    if (t < 64) {
        float v = red[t];
#pragma unroll
        for (int off = 32; off > 0; off >>= 1) v += __shfl_down(v, off);
        if (t == 0) {
            out_scalars[0] = scalarAcc[0] * (1.f / (float)(P_TOTAL * DD));
            out_scalars[1] = expf(v);
        }
    }
}

// ---------------------------------------------------------------------------
// Workspace layout (bytes):
//   z      @ 0        : 16384*32*4  = 2,097,152
//   invz   @ 2097152  : 16384*4     =    65,536
//   en     @ 2162688  : 16384*32*4  = 2,097,152
//   zf16   @ 4259840  : 16384*128   = 2,097,152  (hi|lo f16 rows, x4096)
//   ef16   @ 6356992  : 16384*128   = 2,097,152
//   pval   @ 8454144  : 32*16384*4  = 2,097,152  (also argmax over-read pad)
//   pidx   @ 10551296 : 32*16384*4  = 2,097,152
//   hist   @ 12648448 : 16384*4     =    65,536
//   scalarAcc @ 12713984 : 4*4  (loss, spare, spare, pad)
//   total ~12.7 MB
// ---------------------------------------------------------------------------
extern "C" void kernel_launch(void* const* d_in, const int* in_sizes, int n_in,
                              void* d_out, int out_size, void* d_ws, size_t ws_size,
                              hipStream_t stream)
{
    const float* enc = (const float*)d_in[0];   // [16,512,32,32]
    const float* emb = (const float*)d_in[1];   // [16384,32]
    const float* pw  = (const float*)d_in[2];   // [32,512]
    const float* pb  = (const float*)d_in[3];   // [32]
    const float* ew  = (const float*)d_in[4];   // [512,32]
    const float* eb  = (const float*)d_in[5];   // [512]
    float* out = (float*)d_out;                 // 8388608 + loss + perplexity

    char* ws = (char*)d_ws;
    float* z         = (float*)(ws + 0);
    float* invz      = (float*)(ws + 2097152);
    float* en        = (float*)(ws + 2162688);
    char*  zf16      = ws + 4259840;
    char*  ef16      = ws + 6356992;
    float* pval      = (float*)(ws + 8454144);
    int*   pidx      = (int*)  (ws + 10551296);
    int*   hist      = (int*)  (ws + 12648448);
    float* scalarAcc = (float*)(ws + 12713984);

    prep_kernel   <<<384, 256, 0, stream>>>(enc, pw, pb, emb, z, invz, zf16,
                                            en, ef16, hist, scalarAcc);
    argmax_kernel <<<64 * NCHUNK, 256, 0, stream>>>(zf16, ef16, pval, pidx);
    combex_kernel <<<P_TOTAL / 64, 512, 0, stream>>>(pval, pidx, z, invz, en,
                                                     ew, eb, hist, scalarAcc, out);
    entropy_kernel<<<1, 1024, 0, stream>>>(hist, scalarAcc, out + 8388608);
}

// Round 6
// 224.511 us; speedup vs baseline: 1.0966x; 1.0964x over previous
//
#include <hip/hip_runtime.h>
#include <cstdint>

// Problem constants (from reference setup_inputs)
#define BATCH   16
#define CCH     512
#define DD      32
#define NCODES  16384
#define HWSZ    1024            // 32*32
#define P_TOTAL 16384           // BATCH * HWSZ
#define NCHUNK  32
#define CHUNK   (NCODES / NCHUNK)   // 512 codes per chunk

typedef _Float16 half8 __attribute__((ext_vector_type(8)));
typedef float    f32x4 __attribute__((ext_vector_type(4)));

union H8 { _Float16 h[8]; uint4 u; };
union H4 { _Float16 h[4]; uint2 u; };
union L8 { uint4 u; half8 h; };

// f16 split row layout: row = 128 B = [32 f16 hi | 32 f16 lo], values scaled
// by 2^12 so lo-terms stay in f16 normal range. sim accumulates at scale
// 2^24; argmax is scale-invariant. 4 exact product terms -> ~2^-22 rel err.

// ---------------------------------------------------------------------------
// Kernel PREP (fused): grid 320 blocks x 512 thr.
//   blocks [0,256):  proj  z[p][d] = sum_c enc*pw + pb, invz, zf16 split rows.
//     R12: 64 pos x 8 dgroups(4 d) = 512 thr (was 4 dgroups x 8d = 256 thr).
//     Chip-wide proj waves double to 2048 (2 waves/SIMD): prior shape was
//     1 wave/SIMD -> every HBM/s_load stall fully exposed. pw fetched per
//     16-c batch as float4 row vectors into statically-indexed regs
//     (wave-uniform addr -> broadcast). enc c-loop double-buffered as before.
//   blocks [256,288): enorm en rows + ef16 split rows (512 thr, 1 row each)
//   blocks [288,320): zero hist + scalarAcc
// ---------------------------------------------------------------------------
__global__ __launch_bounds__(512) void prep_kernel(
    const float* __restrict__ enc, const float* __restrict__ pw,
    const float* __restrict__ pb, const float* __restrict__ emb,
    float* __restrict__ z, float* __restrict__ invz, char* __restrict__ zf16,
    float* __restrict__ en, char* __restrict__ ef16,
    int* __restrict__ hist, float* __restrict__ scalarAcc)
{
    const int t = threadIdx.x;

    if (blockIdx.x >= 288) {                 // ---- hist/scalar zeroing ----
        const int i = (blockIdx.x - 288) * 512 + t;
        hist[i] = 0;
        if (blockIdx.x == 288 && t < 4) scalarAcc[t] = 0.f;
        return;
    }

    if (blockIdx.x >= 256) {                 // ---- enorm ----
        const int r = (blockIdx.x - 256) * 512 + t;
        const float4* src = reinterpret_cast<const float4*>(emb + (size_t)r * DD);
        float4 v[8];
        float ssq = 0.f;
#pragma unroll
        for (int q = 0; q < 8; q++) {
            v[q] = src[q];
            ssq += v[q].x * v[q].x + v[q].y * v[q].y + v[q].z * v[q].z + v[q].w * v[q].w;
        }
        const float inv = 1.f / fmaxf(sqrtf(ssq), 1e-6f);
        float4* dst = reinterpret_cast<float4*>(en + (size_t)r * DD);
        char* row = ef16 + (size_t)r * 128;
#pragma unroll
        for (int q = 0; q < 8; q += 2) {
            H8 hi, lo;
#pragma unroll
            for (int u = 0; u < 2; u++) {
                float4 o;
                o.x = v[q + u].x * inv; o.y = v[q + u].y * inv;
                o.z = v[q + u].z * inv; o.w = v[q + u].w * inv;
                dst[q + u] = o;
                const float s[4] = {o.x * 4096.f, o.y * 4096.f, o.z * 4096.f, o.w * 4096.f};
#pragma unroll
                for (int j = 0; j < 4; j++) {
                    const _Float16 h = (_Float16)s[j];
                    hi.h[u * 4 + j] = h;
                    lo.h[u * 4 + j] = (_Float16)(s[j] - (float)h);
                }
            }
            *(uint4*)(row + q * 8)      = hi.u;
            *(uint4*)(row + 64 + q * 8) = lo.u;
        }
        return;
    }

    // ---- proj: 64 positions x 8 dgroups (4 d each) ----
    const int pl  = t & 63;
    const int dg  = __builtin_amdgcn_readfirstlane(t >> 6);   // 0..7 uniform
    const int dg4 = dg * 4;
    const int p0  = blockIdx.x * 64;
    const int b   = p0 >> 10;
    const int hw  = (p0 & 1023) + pl;
    const float* encb = enc + (size_t)b * (CCH * HWSZ) + hw;

    float acc[4];
#pragma unroll
    for (int j = 0; j < 4; j++) acc[j] = 0.f;

    float ev[16];
#pragma unroll
    for (int u = 0; u < 16; u++) ev[u] = encb[(size_t)u * HWSZ];

    for (int c0 = 0; c0 < CCH - 16; c0 += 16) {
        float nv[16];
#pragma unroll
        for (int u = 0; u < 16; u++)             // next enc batch in flight
            nv[u] = encb[(size_t)(c0 + 16 + u) * HWSZ];

        float wf[4][16];                         // pw rows, static-indexed regs
#pragma unroll
        for (int j = 0; j < 4; j++) {
            const float4* rq = reinterpret_cast<const float4*>(pw + (size_t)(dg4 + j) * CCH + c0);
#pragma unroll
            for (int q = 0; q < 4; q++) {
                const float4 wv = rq[q];
                wf[j][q * 4 + 0] = wv.x; wf[j][q * 4 + 1] = wv.y;
                wf[j][q * 4 + 2] = wv.z; wf[j][q * 4 + 3] = wv.w;
            }
        }
#pragma unroll
        for (int u = 0; u < 16; u++)
#pragma unroll
            for (int j = 0; j < 4; j++)
                acc[j] = fmaf(ev[u], wf[j][u], acc[j]);
#pragma unroll
        for (int u = 0; u < 16; u++) ev[u] = nv[u];
    }
    {   // final batch (c0 = CCH-16)
        float wf[4][16];
#pragma unroll
        for (int j = 0; j < 4; j++) {
            const float4* rq = reinterpret_cast<const float4*>(pw + (size_t)(dg4 + j) * CCH + (CCH - 16));
#pragma unroll
            for (int q = 0; q < 4; q++) {
                const float4 wv = rq[q];
                wf[j][q * 4 + 0] = wv.x; wf[j][q * 4 + 1] = wv.y;
                wf[j][q * 4 + 2] = wv.z; wf[j][q * 4 + 3] = wv.w;
            }
        }
#pragma unroll
        for (int u = 0; u < 16; u++)
#pragma unroll
            for (int j = 0; j < 4; j++)
                acc[j] = fmaf(ev[u], wf[j][u], acc[j]);
    }

    const int p = p0 + pl;
    float ssq = 0.f;
    H4 hi, lo;
    float4 zq;
#pragma unroll
    for (int j = 0; j < 4; j++) {
        const float v = acc[j] + pb[dg4 + j];
        ((float*)&zq)[j] = v;
        ssq = fmaf(v, v, ssq);
        const float vs = v * 4096.f;
        const _Float16 h = (_Float16)vs;
        hi.h[j] = h;
        lo.h[j] = (_Float16)(vs - (float)h);
    }
    *reinterpret_cast<float4*>(z + (size_t)p * DD + dg4) = zq;   // 16B-aligned
    char* row = zf16 + (size_t)p * 128;
    *(uint2*)(row + dg * 8)      = hi.u;
    *(uint2*)(row + 64 + dg * 8) = lo.u;

    __shared__ float red[8][64];
    red[dg][pl] = ssq;
    __syncthreads();
    if (t < 64) {
        float tot = red[0][t];
#pragma unroll
        for (int g = 1; g < 8; g++) tot += red[g][t];
        invz[p0 + t] = 1.f / fmaxf(sqrtf(tot), 1e-6f);
    }
}

// ---------------------------------------------------------------------------
// Kernel C: fused MFMA sims + argmax over one 512-code chunk.
// R12 = R7/R10 verbatim (hardware-verified passing, 83us). NOTE: the
// compare-pipelined variant (R9/R11) deterministically corrupts the idx
// population (identical perplexity absmax 2848.0 under two different
// entropy kernels) despite two clean source audits — suspected AGPR
// read-after-MFMA hazard/codegen issue. DO NOT reintroduce without disasm.
// 2 code-tiles per iteration -> every MFMA stage has 8 INDEPENDENT ops;
// best/bidx state split per code-tile (merged post-loop with idx tie-break);
// 2048 blocks, XCD-locality chunk swizzle, 1-iteration (4x16B) prefetch.
// D layout: code=(lane>>4)*4+reg, pos=lane&15; shfl_xor(16,32) reduce with
// equal->lower-idx tie-break (numpy first-occurrence).
// ---------------------------------------------------------------------------
__global__ __launch_bounds__(256, 3) void argmax_kernel(
    const char* __restrict__ zf16, const char* __restrict__ ef16,
    float* __restrict__ pval, int* __restrict__ pidx)
{
    const int w    = threadIdx.x >> 6;       // wave 0..3
    const int lane = threadIdx.x & 63;
    const int col  = lane & 15;
    const int quad = lane >> 4;
    const int chunk = (blockIdx.x & 7) * 4 + (blockIdx.x >> 9);  // XCD swizzle
    const int pg    = (blockIdx.x >> 3) & 63;
    const int wp0   = pg * 256 + w * 64;     // wave position base (64 pos)

    // B fragments (z): pos-tile tt rows wp0 + tt*16 + col
    half8 bh[4], bl[4];
#pragma unroll
    for (int tt = 0; tt < 4; tt++) {
        const char* r = zf16 + (size_t)(wp0 + tt * 16 + col) * 128 + quad * 16;
        L8 a; a.u = *(const uint4*)(r);       bh[tt] = a.h;
        L8 b; b.u = *(const uint4*)(r + 64);  bl[tt] = b.h;
    }

    const int n0 = chunk * CHUNK;
    const char* abase = ef16 + (size_t)(n0 + col) * 128 + quad * 16;

    float best[2][4];
    int   bidx[2][4];
#pragma unroll
    for (int ct = 0; ct < 2; ct++)
#pragma unroll
        for (int tt = 0; tt < 4; tt++) { best[ct][tt] = -3e38f; bidx[ct][tt] = 0; }

    int code = n0 + quad * 4;                // lane's reg-0 code, ctile0 iter0

    // current-iteration A fragments (2 code tiles x hi/lo)
    uint4 c0h = *(const uint4*)(abase);
    uint4 c0l = *(const uint4*)(abase + 64);
    uint4 c1h = *(const uint4*)(abase + 2048);
    uint4 c1l = *(const uint4*)(abase + 2048 + 64);
    const f32x4 zero4 = {0.f, 0.f, 0.f, 0.f};

    for (int it = 0; it < 16; ++it) {
        // prefetch next iteration (last iter over-reads <5KB into pval: safe)
        const char* nx = abase + (size_t)(it + 1) * 4096;
        uint4 n0h = *(const uint4*)(nx);
        uint4 n0l = *(const uint4*)(nx + 64);
        uint4 n1h = *(const uint4*)(nx + 2048);
        uint4 n1l = *(const uint4*)(nx + 2048 + 64);

        L8 u0h, u0l, u1h, u1l;
        u0h.u = c0h; u0l.u = c0l; u1h.u = c1h; u1l.u = c1l;
        const half8 a0h = u0h.h, a0l = u0l.h, a1h = u1h.h, a1l = u1l.h;

        f32x4 acc[2][4];
        // stage 0: hh (8 independent MFMAs)
#pragma unroll
        for (int tt = 0; tt < 4; tt++)
            acc[0][tt] = __builtin_amdgcn_mfma_f32_16x16x32_f16(a0h, bh[tt], zero4, 0, 0, 0);
#pragma unroll
        for (int tt = 0; tt < 4; tt++)
            acc[1][tt] = __builtin_amdgcn_mfma_f32_16x16x32_f16(a1h, bh[tt], zero4, 0, 0, 0);
        // stage 1: hl
#pragma unroll
        for (int tt = 0; tt < 4; tt++)
            acc[0][tt] = __builtin_amdgcn_mfma_f32_16x16x32_f16(a0h, bl[tt], acc[0][tt], 0, 0, 0);
#pragma unroll
        for (int tt = 0; tt < 4; tt++)
            acc[1][tt] = __builtin_amdgcn_mfma_f32_16x16x32_f16(a1h, bl[tt], acc[1][tt], 0, 0, 0);
        // stage 2: lh
#pragma unroll
        for (int tt = 0; tt < 4; tt++)
            acc[0][tt] = __builtin_amdgcn_mfma_f32_16x16x32_f16(a0l, bh[tt], acc[0][tt], 0, 0, 0);
#pragma unroll
        for (int tt = 0; tt < 4; tt++)
            acc[1][tt] = __builtin_amdgcn_mfma_f32_16x16x32_f16(a1l, bh[tt], acc[1][tt], 0, 0, 0);
        // stage 3: ll
#pragma unroll
        for (int tt = 0; tt < 4; tt++)
            acc[0][tt] = __builtin_amdgcn_mfma_f32_16x16x32_f16(a0l, bl[tt], acc[0][tt], 0, 0, 0);
#pragma unroll
        for (int tt = 0; tt < 4; tt++)
            acc[1][tt] = __builtin_amdgcn_mfma_f32_16x16x32_f16(a1l, bl[tt], acc[1][tt], 0, 0, 0);

        // 8 independent compare chains (strict > keeps earliest = lowest code)
#pragma unroll
        for (int ct = 0; ct < 2; ct++)
#pragma unroll
            for (int tt = 0; tt < 4; tt++)
#pragma unroll
                for (int r = 0; r < 4; r++) {
                    const float v = acc[ct][tt][r];
                    if (v > best[ct][tt]) { best[ct][tt] = v; bidx[ct][tt] = code + ct * 16 + r; }
                }

        c0h = n0h; c0l = n0l; c1h = n1h; c1l = n1l;
        code += 32;
    }

    // merge the two code-tile chains (idx tie-break: ct0 iter5 vs ct1 iter3
    // can tie with either idx lower -> full compare)
    float fb[4];
    int   fi[4];
#pragma unroll
    for (int tt = 0; tt < 4; tt++) {
        float b0 = best[0][tt]; int i0 = bidx[0][tt];
        const float b1 = best[1][tt]; const int i1 = bidx[1][tt];
        if (b1 > b0 || (b1 == b0 && i1 < i0)) { b0 = b1; i0 = i1; }
        fb[tt] = b0; fi[tt] = i0;
    }

    // reduce across the 4 quads holding the same position (xor 16, 32)
#pragma unroll
    for (int off = 16; off < 64; off <<= 1) {
#pragma unroll
        for (int tt = 0; tt < 4; tt++) {
            const float ov = __shfl_xor(fb[tt], off);
            const int   oi = __shfl_xor(fi[tt], off);
            if (ov > fb[tt] || (ov == fb[tt] && oi < fi[tt])) {
                fb[tt] = ov; fi[tt] = oi;
            }
        }
    }
    if (quad == 0) {
#pragma unroll
        for (int tt = 0; tt < 4; tt++) {
            pval[(size_t)chunk * P_TOTAL + wp0 + tt * 16 + col] = fb[tt];
            pidx[(size_t)chunk * P_TOTAL + wp0 + tt * 16 + col] = fi[tt];
        }
    }
}

// ---------------------------------------------------------------------------
// Kernel COMBEX (fused combine + expand): 256 blocks x 512 thr, 64 pos each.
// Phase 1 (all 8 waves): per-position partial argmax over 4 chunks/kgroup.
// Phase 2 (wave 0): finalize argmax (idx-compare tie-break = lowest code on
// equal value, correct since chunk idx ranges are ordered), hist atomic,
// quantization-loss (shfl-reduced), stage en[idx] rows into LDS.
// Phase 3 (all): out[b][c][hw] = lat . exp_w[c] + exp_b[c]; ew via s_load.
// idx never round-trips through global memory.
// ---------------------------------------------------------------------------
__global__ __launch_bounds__(512) void combex_kernel(
    const float* __restrict__ pval, const int* __restrict__ pidx,
    const float* __restrict__ z, const float* __restrict__ invz,
    const float* __restrict__ en, const float* __restrict__ ew,
    const float* __restrict__ eb,
    int* __restrict__ hist, float* __restrict__ scalarAcc,
    float* __restrict__ out)
{
    const int t  = threadIdx.x;
    const int p0 = blockIdx.x * 64;

    __shared__ float lat[64 * 33];
    __shared__ float bvs[8][64];
    __shared__ int   bis[8][64];

    {   // phase 1: 8 kgroups x 4 chunks, ascending k (strict > = lowest k)
        const int pl = t & 63;
        const int kg = t >> 6;
        const int p  = p0 + pl;
        float best = -3e38f;
        int   bi   = 0;
#pragma unroll
        for (int k = 0; k < 4; k++) {
            const float v = pval[(size_t)(kg * 4 + k) * P_TOTAL + p];
            const int   i = pidx[(size_t)(kg * 4 + k) * P_TOTAL + p];
            if (v > best) { best = v; bi = i; }
        }
        bvs[kg][pl] = best;
        bis[kg][pl] = bi;
    }
    __syncthreads();

    if (t < 64) {   // phase 2 (wave 0)
        float best = bvs[0][t];
        int   bi   = bis[0][t];
#pragma unroll
        for (int kg = 1; kg < 8; kg++) {
            const float v = bvs[kg][t];
            const int   i = bis[kg][t];
            if (v > best || (v == best && i < bi)) { best = v; bi = i; }
        }
        const int p = p0 + t;
        atomicAdd(&hist[bi], 1);

        const float iv = invz[p];
        const float4* zsrc = reinterpret_cast<const float4*>(z + (size_t)p * DD);
        const float4* esrc = reinterpret_cast<const float4*>(en + (size_t)bi * DD);
        float ls = 0.f;
#pragma unroll
        for (int q = 0; q < 8; q++) {
            const float4 zv = zsrc[q];
            const float4 ev = esrc[q];
            lat[t * 33 + q * 4 + 0] = ev.x;
            lat[t * 33 + q * 4 + 1] = ev.y;
            lat[t * 33 + q * 4 + 2] = ev.z;
            lat[t * 33 + q * 4 + 3] = ev.w;
            const float dx = zv.x * iv - ev.x;
            const float dy = zv.y * iv - ev.y;
            const float dz = zv.z * iv - ev.z;
            const float dw = zv.w * iv - ev.w;
            ls += dx * dx + dy * dy + dz * dz + dw * dw;
        }
#pragma unroll
        for (int off = 32; off > 0; off >>= 1) ls += __shfl_down(ls, off);
        if (t == 0) atomicAdd(&scalarAcc[0], ls);
    }
    __syncthreads();

    // phase 3: expand — 8 waves x 64 c each
    const int hw_l = t & 63;
    const int cg   = __builtin_amdgcn_readfirstlane(t >> 6);   // 0..7
    float lr[32];
#pragma unroll
    for (int d = 0; d < DD; d++) lr[d] = lat[hw_l * 33 + d];

    const int b   = p0 >> 10;
    const int hw0 = p0 & 1023;
    float* outb = out + (size_t)b * (CCH * HWSZ) + hw0 + hw_l;
    const int c0 = cg * 64;
#pragma unroll 4
    for (int k = 0; k < 64; k++) {
        const int c = c0 + k;
        const float* ewc = ew + (size_t)c * DD;      // uniform -> s_load
        float s0 = 0.f, s1 = 0.f, s2 = 0.f, s3 = 0.f;
#pragma unroll
        for (int d = 0; d < DD; d += 4) {
            s0 = fmaf(lr[d + 0], ewc[d + 0], s0);
            s1 = fmaf(lr[d + 1], ewc[d + 1], s1);
            s2 = fmaf(lr[d + 2], ewc[d + 2], s2);
            s3 = fmaf(lr[d + 3], ewc[d + 3], s3);
        }
        outb[(size_t)c * HWSZ] = (s0 + s1) + (s2 + s3) + eb[c];
    }
}

// ---------------------------------------------------------------------------
// Kernel ENTROPY: SINGLE block, 1024 threads, 16 hist entries each.
// Race-free by construction: no cross-block done-counter, no fences.
// combex's atomicAdds (hist, scalarAcc[0]) are visible via stream-ordered
// kernel boundaries. Shared-mem tree + wave shuffle reduce; thread 0
// writes both scalar outputs.
// ---------------------------------------------------------------------------
__global__ __launch_bounds__(1024) void entropy_kernel(
    const int* __restrict__ hist, const float* __restrict__ scalarAcc,
    float* __restrict__ out_scalars)
{
    const int t = threadIdx.x;
    float h = 0.f;
#pragma unroll
    for (int k = 0; k < 16; k++) {
        const float u = (float)hist[t + k * 1024] * (1.f / (float)P_TOTAL);
        h += -u * logf(u + 1e-6f);
    }
    __shared__ float red[1024];
    red[t] = h;
    __syncthreads();
#pragma unroll
    for (int s = 512; s >= 64; s >>= 1) {
        if (t < s) red[t] += red[t + s];
        __syncthreads();
    }
    if (t < 64) {
        float v = red[t];
#pragma unroll
        for (int off = 32; off > 0; off >>= 1) v += __shfl_down(v, off);
        if (t == 0) {
            out_scalars[0] = scalarAcc[0] * (1.f / (float)(P_TOTAL * DD));
            out_scalars[1] = expf(v);
        }
    }
}

// ---------------------------------------------------------------------------
// Workspace layout (bytes):
//   z      @ 0        : 16384*32*4  = 2,097,152
//   invz   @ 2097152  : 16384*4     =    65,536
//   en     @ 2162688  : 16384*32*4  = 2,097,152
//   zf16   @ 4259840  : 16384*128   = 2,097,152  (hi|lo f16 rows, x4096)
//   ef16   @ 6356992  : 16384*128   = 2,097,152
//   pval   @ 8454144  : 32*16384*4  = 2,097,152  (also argmax over-read pad)
//   pidx   @ 10551296 : 32*16384*4  = 2,097,152
//   hist   @ 12648448 : 16384*4     =    65,536
//   scalarAcc @ 12713984 : 4*4  (loss, spare, spare, pad)
//   total ~12.7 MB
// ---------------------------------------------------------------------------
extern "C" void kernel_launch(void* const* d_in, const int* in_sizes, int n_in,
                              void* d_out, int out_size, void* d_ws, size_t ws_size,
                              hipStream_t stream)
{
    const float* enc = (const float*)d_in[0];   // [16,512,32,32]
    const float* emb = (const float*)d_in[1];   // [16384,32]
    const float* pw  = (const float*)d_in[2];   // [32,512]
    const float* pb  = (const float*)d_in[3];   // [32]
    const float* ew  = (const float*)d_in[4];   // [512,32]
    const float* eb  = (const float*)d_in[5];   // [512]
    float* out = (float*)d_out;                 // 8388608 + loss + perplexity

    char* ws = (char*)d_ws;
    float* z         = (float*)(ws + 0);
    float* invz      = (float*)(ws + 2097152);
    float* en        = (float*)(ws + 2162688);
    char*  zf16      = ws + 4259840;
    char*  ef16      = ws + 6356992;
    float* pval      = (float*)(ws + 8454144);
    int*   pidx      = (int*)  (ws + 10551296);
    int*   hist      = (int*)  (ws + 12648448);
    float* scalarAcc = (float*)(ws + 12713984);

    prep_kernel   <<<320, 512, 0, stream>>>(enc, pw, pb, emb, z, invz, zf16,
                                            en, ef16, hist, scalarAcc);
    argmax_kernel <<<64 * NCHUNK, 256, 0, stream>>>(zf16, ef16, pval, pidx);
    combex_kernel <<<P_TOTAL / 64, 512, 0, stream>>>(pval, pidx, z, invz, en,
                                                     ew, eb, hist, scalarAcc, out);
    entropy_kernel<<<1, 1024, 0, stream>>>(hist, scalarAcc, out + 8388608);
}

// Round 7
// 205.143 us; speedup vs baseline: 1.2001x; 1.0944x over previous
//
#include <hip/hip_runtime.h>
#include <cstdint>

// Problem constants (from reference setup_inputs)
#define BATCH   16
#define CCH     512
#define DD      32
#define NCODES  16384
#define HWSZ    1024            // 32*32
#define P_TOTAL 16384           // BATCH * HWSZ
#define NCHUNK  32
#define CHUNK   (NCODES / NCHUNK)   // 512 codes per chunk

typedef _Float16 half8 __attribute__((ext_vector_type(8)));
typedef float    f32x4 __attribute__((ext_vector_type(4)));

union H8 { _Float16 h[8]; uint4 u; };
union H4 { _Float16 h[4]; uint2 u; };
union L8 { uint4 u; half8 h; };

// f16 split row layout: row = 128 B = [32 f16 hi | 32 f16 lo], values scaled
// by 2^12 so lo-terms stay in f16 normal range. sim accumulates at scale
// 2^24; argmax is scale-invariant. 4 exact product terms -> ~2^-22 rel err.

// ---------------------------------------------------------------------------
// Kernel PREP (fused): grid 320 blocks x 512 thr.
//   blocks [0,256):  proj  z[p][d] = sum_c enc*pw + pb, invz, zf16 split rows.
//     64 pos x 8 dgroups(4 d) = 512 thr; enc c-loop double-buffered.
//     R13: pw (64KB) staged to LDS once per block (coalesced), then read as
//     wave-uniform broadcast ds_read_b128 — weight access no longer depends
//     on the compiler proving s_load-ability of readfirstlane-derived
//     pointers (suspected per-lane VMEM storm = the invisible time).
//   blocks [256,288): enorm en rows + ef16 split rows (512 thr, 1 row each)
//   blocks [288,320): zero hist + scalarAcc
// ---------------------------------------------------------------------------
__global__ __launch_bounds__(512) void prep_kernel(
    const float* __restrict__ enc, const float* __restrict__ pw,
    const float* __restrict__ pb, const float* __restrict__ emb,
    float* __restrict__ z, float* __restrict__ invz, char* __restrict__ zf16,
    float* __restrict__ en, char* __restrict__ ef16,
    int* __restrict__ hist, float* __restrict__ scalarAcc)
{
    const int t = threadIdx.x;
    __shared__ float pwlds[DD * CCH];        // 64KB: pw[32][512] staged
    __shared__ float red[8][64];             // ssq partials

    if (blockIdx.x >= 288) {                 // ---- hist/scalar zeroing ----
        const int i = (blockIdx.x - 288) * 512 + t;
        hist[i] = 0;
        if (blockIdx.x == 288 && t < 4) scalarAcc[t] = 0.f;
        return;
    }

    if (blockIdx.x >= 256) {                 // ---- enorm ----
        const int r = (blockIdx.x - 256) * 512 + t;
        const float4* src = reinterpret_cast<const float4*>(emb + (size_t)r * DD);
        float4 v[8];
        float ssq = 0.f;
#pragma unroll
        for (int q = 0; q < 8; q++) {
            v[q] = src[q];
            ssq += v[q].x * v[q].x + v[q].y * v[q].y + v[q].z * v[q].z + v[q].w * v[q].w;
        }
        const float inv = 1.f / fmaxf(sqrtf(ssq), 1e-6f);
        float4* dst = reinterpret_cast<float4*>(en + (size_t)r * DD);
        char* row = ef16 + (size_t)r * 128;
#pragma unroll
        for (int q = 0; q < 8; q += 2) {
            H8 hi, lo;
#pragma unroll
            for (int u = 0; u < 2; u++) {
                float4 o;
                o.x = v[q + u].x * inv; o.y = v[q + u].y * inv;
                o.z = v[q + u].z * inv; o.w = v[q + u].w * inv;
                dst[q + u] = o;
                const float s[4] = {o.x * 4096.f, o.y * 4096.f, o.z * 4096.f, o.w * 4096.f};
#pragma unroll
                for (int j = 0; j < 4; j++) {
                    const _Float16 h = (_Float16)s[j];
                    hi.h[u * 4 + j] = h;
                    lo.h[u * 4 + j] = (_Float16)(s[j] - (float)h);
                }
            }
            *(uint4*)(row + q * 8)      = hi.u;
            *(uint4*)(row + 64 + q * 8) = lo.u;
        }
        return;
    }

    // ---- proj: 64 positions x 8 dgroups (4 d each) ----
    const int pl  = t & 63;
    const int dg  = __builtin_amdgcn_readfirstlane(t >> 6);   // 0..7 uniform
    const int dg4 = dg * 4;
    const int p0  = blockIdx.x * 64;
    const int b   = p0 >> 10;
    const int hw  = (p0 & 1023) + pl;
    const float* encb = enc + (size_t)b * (CCH * HWSZ) + hw;

    float ev[16];
#pragma unroll
    for (int u = 0; u < 16; u++) ev[u] = encb[(size_t)u * HWSZ];   // first batch

    {   // stage pw -> LDS (coalesced, 8 float4 per thread)
        const float4* pws = reinterpret_cast<const float4*>(pw);
        float4* pwl = reinterpret_cast<float4*>(pwlds);
#pragma unroll
        for (int i = 0; i < 8; i++) pwl[t + i * 512] = pws[t + i * 512];
    }
    __syncthreads();

    float acc[4];
#pragma unroll
    for (int j = 0; j < 4; j++) acc[j] = 0.f;

    for (int c0 = 0; c0 < CCH - 16; c0 += 16) {
        float nv[16];
#pragma unroll
        for (int u = 0; u < 16; u++)             // next enc batch in flight
            nv[u] = encb[(size_t)(c0 + 16 + u) * HWSZ];

        float wf[4][16];                         // pw rows via LDS broadcast
#pragma unroll
        for (int j = 0; j < 4; j++) {
            const float4* rq = reinterpret_cast<const float4*>(&pwlds[(dg4 + j) * CCH + c0]);
#pragma unroll
            for (int q = 0; q < 4; q++) {
                const float4 wv = rq[q];
                wf[j][q * 4 + 0] = wv.x; wf[j][q * 4 + 1] = wv.y;
                wf[j][q * 4 + 2] = wv.z; wf[j][q * 4 + 3] = wv.w;
            }
        }
#pragma unroll
        for (int u = 0; u < 16; u++)
#pragma unroll
            for (int j = 0; j < 4; j++)
                acc[j] = fmaf(ev[u], wf[j][u], acc[j]);
#pragma unroll
        for (int u = 0; u < 16; u++) ev[u] = nv[u];
    }
    {   // final batch (c0 = CCH-16)
        float wf[4][16];
#pragma unroll
        for (int j = 0; j < 4; j++) {
            const float4* rq = reinterpret_cast<const float4*>(&pwlds[(dg4 + j) * CCH + (CCH - 16)]);
#pragma unroll
            for (int q = 0; q < 4; q++) {
                const float4 wv = rq[q];
                wf[j][q * 4 + 0] = wv.x; wf[j][q * 4 + 1] = wv.y;
                wf[j][q * 4 + 2] = wv.z; wf[j][q * 4 + 3] = wv.w;
            }
        }
#pragma unroll
        for (int u = 0; u < 16; u++)
#pragma unroll
            for (int j = 0; j < 4; j++)
                acc[j] = fmaf(ev[u], wf[j][u], acc[j]);
    }

    const int p = p0 + pl;
    float ssq = 0.f;
    H4 hi, lo;
    float4 zq;
#pragma unroll
    for (int j = 0; j < 4; j++) {
        const float v = acc[j] + pb[dg4 + j];
        ((float*)&zq)[j] = v;
        ssq = fmaf(v, v, ssq);
        const float vs = v * 4096.f;
        const _Float16 h = (_Float16)vs;
        hi.h[j] = h;
        lo.h[j] = (_Float16)(vs - (float)h);
    }
    *reinterpret_cast<float4*>(z + (size_t)p * DD + dg4) = zq;   // 16B-aligned
    char* row = zf16 + (size_t)p * 128;
    *(uint2*)(row + dg * 8)      = hi.u;
    *(uint2*)(row + 64 + dg * 8) = lo.u;

    red[dg][pl] = ssq;
    __syncthreads();
    if (t < 64) {
        float tot = red[0][t];
#pragma unroll
        for (int g = 1; g < 8; g++) tot += red[g][t];
        invz[p0 + t] = 1.f / fmaxf(sqrtf(tot), 1e-6f);
    }
}

// ---------------------------------------------------------------------------
// Kernel C: fused MFMA sims + argmax over one 512-code chunk.
// R7/R10 verbatim (hardware-verified passing, 83us). NOTE: the
// compare-pipelined variant (R9/R11) deterministically corrupts the idx
// population (identical perplexity absmax 2848.0 under two different
// entropy kernels) despite two clean source audits — suspected AGPR
// read-after-MFMA hazard/codegen issue. DO NOT reintroduce without disasm.
// 2 code-tiles per iteration -> every MFMA stage has 8 INDEPENDENT ops;
// best/bidx state split per code-tile (merged post-loop with idx tie-break);
// 2048 blocks, XCD-locality chunk swizzle, 1-iteration (4x16B) prefetch.
// D layout: code=(lane>>4)*4+reg, pos=lane&15; shfl_xor(16,32) reduce with
// equal->lower-idx tie-break (numpy first-occurrence).
// ---------------------------------------------------------------------------
__global__ __launch_bounds__(256, 3) void argmax_kernel(
    const char* __restrict__ zf16, const char* __restrict__ ef16,
    float* __restrict__ pval, int* __restrict__ pidx)
{
    const int w    = threadIdx.x >> 6;       // wave 0..3
    const int lane = threadIdx.x & 63;
    const int col  = lane & 15;
    const int quad = lane >> 4;
    const int chunk = (blockIdx.x & 7) * 4 + (blockIdx.x >> 9);  // XCD swizzle
    const int pg    = (blockIdx.x >> 3) & 63;
    const int wp0   = pg * 256 + w * 64;     // wave position base (64 pos)

    // B fragments (z): pos-tile tt rows wp0 + tt*16 + col
    half8 bh[4], bl[4];
#pragma unroll
    for (int tt = 0; tt < 4; tt++) {
        const char* r = zf16 + (size_t)(wp0 + tt * 16 + col) * 128 + quad * 16;
        L8 a; a.u = *(const uint4*)(r);       bh[tt] = a.h;
        L8 b; b.u = *(const uint4*)(r + 64);  bl[tt] = b.h;
    }

    const int n0 = chunk * CHUNK;
    const char* abase = ef16 + (size_t)(n0 + col) * 128 + quad * 16;

    float best[2][4];
    int   bidx[2][4];
#pragma unroll
    for (int ct = 0; ct < 2; ct++)
#pragma unroll
        for (int tt = 0; tt < 4; tt++) { best[ct][tt] = -3e38f; bidx[ct][tt] = 0; }

    int code = n0 + quad * 4;                // lane's reg-0 code, ctile0 iter0

    // current-iteration A fragments (2 code tiles x hi/lo)
    uint4 c0h = *(const uint4*)(abase);
    uint4 c0l = *(const uint4*)(abase + 64);
    uint4 c1h = *(const uint4*)(abase + 2048);
    uint4 c1l = *(const uint4*)(abase + 2048 + 64);
    const f32x4 zero4 = {0.f, 0.f, 0.f, 0.f};

    for (int it = 0; it < 16; ++it) {
        // prefetch next iteration (last iter over-reads <5KB into pval: safe)
        const char* nx = abase + (size_t)(it + 1) * 4096;
        uint4 n0h = *(const uint4*)(nx);
        uint4 n0l = *(const uint4*)(nx + 64);
        uint4 n1h = *(const uint4*)(nx + 2048);
        uint4 n1l = *(const uint4*)(nx + 2048 + 64);

        L8 u0h, u0l, u1h, u1l;
        u0h.u = c0h; u0l.u = c0l; u1h.u = c1h; u1l.u = c1l;
        const half8 a0h = u0h.h, a0l = u0l.h, a1h = u1h.h, a1l = u1l.h;

        f32x4 acc[2][4];
        // stage 0: hh (8 independent MFMAs)
#pragma unroll
        for (int tt = 0; tt < 4; tt++)
            acc[0][tt] = __builtin_amdgcn_mfma_f32_16x16x32_f16(a0h, bh[tt], zero4, 0, 0, 0);
#pragma unroll
        for (int tt = 0; tt < 4; tt++)
            acc[1][tt] = __builtin_amdgcn_mfma_f32_16x16x32_f16(a1h, bh[tt], zero4, 0, 0, 0);
        // stage 1: hl
#pragma unroll
        for (int tt = 0; tt < 4; tt++)
            acc[0][tt] = __builtin_amdgcn_mfma_f32_16x16x32_f16(a0h, bl[tt], acc[0][tt], 0, 0, 0);
#pragma unroll
        for (int tt = 0; tt < 4; tt++)
            acc[1][tt] = __builtin_amdgcn_mfma_f32_16x16x32_f16(a1h, bl[tt], acc[1][tt], 0, 0, 0);
        // stage 2: lh
#pragma unroll
        for (int tt = 0; tt < 4; tt++)
            acc[0][tt] = __builtin_amdgcn_mfma_f32_16x16x32_f16(a0l, bh[tt], acc[0][tt], 0, 0, 0);
#pragma unroll
        for (int tt = 0; tt < 4; tt++)
            acc[1][tt] = __builtin_amdgcn_mfma_f32_16x16x32_f16(a1l, bh[tt], acc[1][tt], 0, 0, 0);
        // stage 3: ll
#pragma unroll
        for (int tt = 0; tt < 4; tt++)
            acc[0][tt] = __builtin_amdgcn_mfma_f32_16x16x32_f16(a0l, bl[tt], acc[0][tt], 0, 0, 0);
#pragma unroll
        for (int tt = 0; tt < 4; tt++)
            acc[1][tt] = __builtin_amdgcn_mfma_f32_16x16x32_f16(a1l, bl[tt], acc[1][tt], 0, 0, 0);

        // 8 independent compare chains (strict > keeps earliest = lowest code)
#pragma unroll
        for (int ct = 0; ct < 2; ct++)
#pragma unroll
            for (int tt = 0; tt < 4; tt++)
#pragma unroll
                for (int r = 0; r < 4; r++) {
                    const float v = acc[ct][tt][r];
                    if (v > best[ct][tt]) { best[ct][tt] = v; bidx[ct][tt] = code + ct * 16 + r; }
                }

        c0h = n0h; c0l = n0l; c1h = n1h; c1l = n1l;
        code += 32;
    }

    // merge the two code-tile chains (idx tie-break: ct0 iter5 vs ct1 iter3
    // can tie with either idx lower -> full compare)
    float fb[4];
    int   fi[4];
#pragma unroll
    for (int tt = 0; tt < 4; tt++) {
        float b0 = best[0][tt]; int i0 = bidx[0][tt];
        const float b1 = best[1][tt]; const int i1 = bidx[1][tt];
        if (b1 > b0 || (b1 == b0 && i1 < i0)) { b0 = b1; i0 = i1; }
        fb[tt] = b0; fi[tt] = i0;
    }

    // reduce across the 4 quads holding the same position (xor 16, 32)
#pragma unroll
    for (int off = 16; off < 64; off <<= 1) {
#pragma unroll
        for (int tt = 0; tt < 4; tt++) {
            const float ov = __shfl_xor(fb[tt], off);
            const int   oi = __shfl_xor(fi[tt], off);
            if (ov > fb[tt] || (ov == fb[tt] && oi < fi[tt])) {
                fb[tt] = ov; fi[tt] = oi;
            }
        }
    }
    if (quad == 0) {
#pragma unroll
        for (int tt = 0; tt < 4; tt++) {
            pval[(size_t)chunk * P_TOTAL + wp0 + tt * 16 + col] = fb[tt];
            pidx[(size_t)chunk * P_TOTAL + wp0 + tt * 16 + col] = fi[tt];
        }
    }
}

// ---------------------------------------------------------------------------
// Kernel COMBEX (fused combine + expand): 256 blocks x 512 thr, 64 pos each.
// R13: ew (64KB) staged to LDS at block start (coalesced; overlaps phase 1;
// covered by phase-1 barrier) — phase 3 reads it as wave-uniform broadcast
// ds_read instead of relying on s_load uniformity proofs. Phase 2 now
// parallel across all 512 threads (pos = t&63, part = t>>6: each part
// gathers 4 floats of en[bi]/z[p], loss partials via lred; wave 0
// finalizes loss overlapped with phase 3).
// Phase 1 (all 8 waves): per-position partial argmax over 4 chunks/kgroup.
// Phase 3 (all): out[b][c][hw] = lat . exp_w[c] + exp_b[c] from LDS.
// idx never round-trips through global memory.
// ---------------------------------------------------------------------------
__global__ __launch_bounds__(512) void combex_kernel(
    const float* __restrict__ pval, const int* __restrict__ pidx,
    const float* __restrict__ z, const float* __restrict__ invz,
    const float* __restrict__ en, const float* __restrict__ ew,
    const float* __restrict__ eb,
    int* __restrict__ hist, float* __restrict__ scalarAcc,
    float* __restrict__ out)
{
    const int t  = threadIdx.x;
    const int p0 = blockIdx.x * 64;

    __shared__ float lat[64 * 33];           // stride 33: conflict-free reads
    __shared__ float bvs[8][64];
    __shared__ int   bis[8][64];
    __shared__ float ewlds[CCH * DD];        // 64KB: ew[512][32] staged
    __shared__ float lred[8][64];            // loss partials [part][pos]

    {   // stage ew -> LDS (coalesced, 8 float4 per thread); no barrier here —
        // the phase-1 barrier below covers it.
        const float4* ews = reinterpret_cast<const float4*>(ew);
        float4* ewl = reinterpret_cast<float4*>(ewlds);
#pragma unroll
        for (int i = 0; i < 8; i++) ewl[t + i * 512] = ews[t + i * 512];
    }

    {   // phase 1: 8 kgroups x 4 chunks, ascending k (strict > = lowest k)
        const int pl = t & 63;
        const int kg = t >> 6;
        const int p  = p0 + pl;
        float best = -3e38f;
        int   bi   = 0;
#pragma unroll
        for (int k = 0; k < 4; k++) {
            const float v = pval[(size_t)(kg * 4 + k) * P_TOTAL + p];
            const int   i = pidx[(size_t)(kg * 4 + k) * P_TOTAL + p];
            if (v > best) { best = v; bi = i; }
        }
        bvs[kg][pl] = best;
        bis[kg][pl] = bi;
    }
    __syncthreads();

    {   // phase 2 (all 512 threads): pos = t&63, part = t>>6.
        // All parts redundantly finalize the argmax for their pos
        // (deterministic: same LDS data, same ops); part 0 does the hist add.
        const int pos  = t & 63;
        const int part = t >> 6;
        float best = bvs[0][pos];
        int   bi   = bis[0][pos];
#pragma unroll
        for (int kg = 1; kg < 8; kg++) {
            const float v = bvs[kg][pos];
            const int   i = bis[kg][pos];
            if (v > best || (v == best && i < bi)) { best = v; bi = i; }
        }
        if (part == 0) atomicAdd(&hist[bi], 1);
        const int p = p0 + pos;
        const float iv = invz[p];
        const float4 zv  = *reinterpret_cast<const float4*>(z  + (size_t)p  * DD + part * 4);
        const float4 evv = *reinterpret_cast<const float4*>(en + (size_t)bi * DD + part * 4);
        lat[pos * 33 + part * 4 + 0] = evv.x;
        lat[pos * 33 + part * 4 + 1] = evv.y;
        lat[pos * 33 + part * 4 + 2] = evv.z;
        lat[pos * 33 + part * 4 + 3] = evv.w;
        const float dx = zv.x * iv - evv.x;
        const float dy = zv.y * iv - evv.y;
        const float dz = zv.z * iv - evv.z;
        const float dw = zv.w * iv - evv.w;
        lred[part][pos] = dx * dx + dy * dy + dz * dz + dw * dw;
    }
    __syncthreads();

    // loss finalize (wave 0) — overlaps the other waves' phase 3
    if (t < 64) {
        float ls = lred[0][t];
#pragma unroll
        for (int g = 1; g < 8; g++) ls += lred[g][t];
#pragma unroll
        for (int off = 32; off > 0; off >>= 1) ls += __shfl_down(ls, off);
        if (t == 0) atomicAdd(&scalarAcc[0], ls);
    }

    // phase 3: expand — 8 waves x 64 c each, weights from LDS
    const int hw_l = t & 63;
    const int cg   = __builtin_amdgcn_readfirstlane(t >> 6);   // 0..7
    float lr[32];
#pragma unroll
    for (int d = 0; d < DD; d++) lr[d] = lat[hw_l * 33 + d];

    const int b   = p0 >> 10;
    const int hw0 = p0 & 1023;
    float* outb = out + (size_t)b * (CCH * HWSZ) + hw0 + hw_l;
    const int c0 = cg * 64;
#pragma unroll 4
    for (int k = 0; k < 64; k++) {
        const int c = c0 + k;
        const float* ewc = &ewlds[(size_t)c * DD];   // uniform -> broadcast
        float s0 = 0.f, s1 = 0.f, s2 = 0.f, s3 = 0.f;
#pragma unroll
        for (int d = 0; d < DD; d += 4) {
            s0 = fmaf(lr[d + 0], ewc[d + 0], s0);
            s1 = fmaf(lr[d + 1], ewc[d + 1], s1);
            s2 = fmaf(lr[d + 2], ewc[d + 2], s2);
            s3 = fmaf(lr[d + 3], ewc[d + 3], s3);
        }
        outb[(size_t)c * HWSZ] = (s0 + s1) + (s2 + s3) + eb[c];
    }
}

// ---------------------------------------------------------------------------
// Kernel ENTROPY: SINGLE block, 1024 threads, 16 hist entries each.
// Race-free by construction: no cross-block done-counter, no fences.
// combex's atomicAdds (hist, scalarAcc[0]) are visible via stream-ordered
// kernel boundaries. Shared-mem tree + wave shuffle reduce; thread 0
// writes both scalar outputs.
// ---------------------------------------------------------------------------
__global__ __launch_bounds__(1024) void entropy_kernel(
    const int* __restrict__ hist, const float* __restrict__ scalarAcc,
    float* __restrict__ out_scalars)
{
    const int t = threadIdx.x;
    float h = 0.f;
#pragma unroll
    for (int k = 0; k < 16; k++) {
        const float u = (float)hist[t + k * 1024] * (1.f / (float)P_TOTAL);
        h += -u * logf(u + 1e-6f);
    }
    __shared__ float red[1024];
    red[t] = h;
    __syncthreads();
#pragma unroll
    for (int s = 512; s >= 64; s >>= 1) {
        if (t < s) red[t] += red[t + s];
        __syncthreads();
    }
    if (t < 64) {
        float v = red[t];
#pragma unroll
        for (int off = 32; off > 0; off >>= 1) v += __shfl_down(v, off);
        if (t == 0) {
            out_scalars[0] = scalarAcc[0] * (1.f / (float)(P_TOTAL * DD));
            out_scalars[1] = expf(v);
        }
    }
}

// ---------------------------------------------------------------------------
// Workspace layout (bytes):
//   z      @ 0        : 16384*32*4  = 2,097,152
//   invz   @ 2097152  : 16384*4     =    65,536
//   en     @ 2162688  : 16384*32*4  = 2,097,152
//   zf16   @ 4259840  : 16384*128   = 2,097,152  (hi|lo f16 rows, x4096)
//   ef16   @ 6356992  : 16384*128   = 2,097,152
//   pval   @ 8454144  : 32*16384*4  = 2,097,152  (also argmax over-read pad)
//   pidx   @ 10551296 : 32*16384*4  = 2,097,152
//   hist   @ 12648448 : 16384*4     =    65,536
//   scalarAcc @ 12713984 : 4*4  (loss, spare, spare, pad)
//   total ~12.7 MB
// ---------------------------------------------------------------------------
extern "C" void kernel_launch(void* const* d_in, const int* in_sizes, int n_in,
                              void* d_out, int out_size, void* d_ws, size_t ws_size,
                              hipStream_t stream)
{
    const float* enc = (const float*)d_in[0];   // [16,512,32,32]
    const float* emb = (const float*)d_in[1];   // [16384,32]
    const float* pw  = (const float*)d_in[2];   // [32,512]
    const float* pb  = (const float*)d_in[3];   // [32]
    const float* ew  = (const float*)d_in[4];   // [512,32]
    const float* eb  = (const float*)d_in[5];   // [512]
    float* out = (float*)d_out;                 // 8388608 + loss + perplexity

    char* ws = (char*)d_ws;
    float* z         = (float*)(ws + 0);
    float* invz      = (float*)(ws + 2097152);
    float* en        = (float*)(ws + 2162688);
    char*  zf16      = ws + 4259840;
    char*  ef16      = ws + 6356992;
    float* pval      = (float*)(ws + 8454144);
    int*   pidx      = (int*)  (ws + 10551296);
    int*   hist      = (int*)  (ws + 12648448);
    float* scalarAcc = (float*)(ws + 12713984);

    prep_kernel   <<<320, 512, 0, stream>>>(enc, pw, pb, emb, z, invz, zf16,
                                            en, ef16, hist, scalarAcc);
    argmax_kernel <<<64 * NCHUNK, 256, 0, stream>>>(zf16, ef16, pval, pidx);
    combex_kernel <<<P_TOTAL / 64, 512, 0, stream>>>(pval, pidx, z, invz, en,
                                                     ew, eb, hist, scalarAcc, out);
    entropy_kernel<<<1, 1024, 0, stream>>>(hist, scalarAcc, out + 8388608);
}